// Round 1
// baseline (323.305 us; speedup 1.0000x reference)
//
#include <hip/hip_runtime.h>

#define C0 0.28209479177387814f
#define C1 0.4886025119029199f

__device__ __forceinline__ float sigmoidf(float x) {
    return 1.0f / (1.0f + expf(-x));
}

// ---------------------------------------------------------------------------
// Vectorized kernel: 4 gaussians per thread, all global traffic as float4.
// Requires N % 4 == 0 (true for the bench: N = 2,000,000), which also keeps
// the packed-output sub-buffer bases (out+3N, out+12N, out+15N) 16B-aligned.
// ---------------------------------------------------------------------------
__global__ __launch_bounds__(256) void gauss_kernel_v4(
    const float4* __restrict__ vd4,    // N/4 groups * 3
    const float4* __restrict__ xyz4,   // * 3
    const float4* __restrict__ sl4,    // * 3
    const float4* __restrict__ rq4,    // * 4
    const float4* __restrict__ ol4,    // * 1
    const float4* __restrict__ sh4,    // * 12
    float4* __restrict__ oxyz4,        // * 3
    float4* __restrict__ ocov4,        // * 9
    float4* __restrict__ orgb4,        // * 3
    float4* __restrict__ oop4,         // * 1
    int N4)
{
    int g = blockIdx.x * blockDim.x + threadIdx.x;
    if (g >= N4) return;

    // ---- coalesced 16B loads ----
    float4 va = vd4[3*g+0], vb = vd4[3*g+1], vc = vd4[3*g+2];
    float4 pa = xyz4[3*g+0], pb = xyz4[3*g+1], pc = xyz4[3*g+2];
    float4 sa = sl4[3*g+0], sb = sl4[3*g+1], sc = sl4[3*g+2];
    float4 q[4];
    #pragma unroll
    for (int k = 0; k < 4; ++k) q[k] = rq4[4*g+k];
    float4 ol = ol4[g];
    float4 shv[12];
    #pragma unroll
    for (int j = 0; j < 12; ++j) shv[j] = sh4[12*g+j];

    // ---- unpack AoS-of-3 into per-item lanes (compile-time shuffles) ----
    float vx[4] = {va.x, va.w, vb.z, vc.y};
    float vy[4] = {va.y, vb.x, vb.w, vc.z};
    float vz[4] = {va.z, vb.y, vc.x, vc.w};

    float slx[4] = {sa.x, sa.w, sb.z, sc.y};
    float sly[4] = {sa.y, sb.x, sb.w, sc.z};
    float slz[4] = {sa.z, sb.y, sc.x, sc.w};

    float opl[4] = {ol.x, ol.y, ol.z, ol.w};

    float cov[36];
    float rgb[12];
    float opv[4];

    #pragma unroll
    for (int k = 0; k < 4; ++k) {
        // ---- rgb: degree-1 SH then sigmoid ----
        float4 c0 = shv[3*k+0];
        float4 c1 = shv[3*k+1];
        float4 c2 = shv[3*k+2];
        float r0 = C0*c0.x - C1*vy[k]*c0.y + C1*vz[k]*c0.z - C1*vx[k]*c0.w;
        float r1 = C0*c1.x - C1*vy[k]*c1.y + C1*vz[k]*c1.z - C1*vx[k]*c1.w;
        float r2 = C0*c2.x - C1*vy[k]*c2.y + C1*vz[k]*c2.z - C1*vx[k]*c2.w;
        rgb[3*k+0] = sigmoidf(r0);
        rgb[3*k+1] = sigmoidf(r1);
        rgb[3*k+2] = sigmoidf(r2);

        // ---- opacity ----
        opv[k] = sigmoidf(opl[k]);

        // ---- rotation from normalized quaternion ----
        float qr = q[k].x, qx = q[k].y, qy = q[k].z, qz = q[k].w;
        float nrm = sqrtf(qr*qr + qx*qx + qy*qy + qz*qz);
        float inv = 1.0f / fmaxf(nrm, 1e-12f);
        float r = qr*inv, x = qx*inv, y = qy*inv, z = qz*inv;

        float R00 = 1.0f - 2.0f*(y*y + z*z);
        float R01 = 2.0f*(x*y - r*z);
        float R02 = 2.0f*(x*z + r*y);
        float R10 = 2.0f*(x*y + r*z);
        float R11 = 1.0f - 2.0f*(x*x + z*z);
        float R12 = 2.0f*(y*z - r*x);
        float R20 = 2.0f*(x*z - r*y);
        float R21 = 2.0f*(y*z + r*x);
        float R22 = 1.0f - 2.0f*(x*x + y*y);

        // ---- M = R * diag(scale) ; cov = M * M^T ----
        float s0 = expf(slx[k]), s1 = expf(sly[k]), s2 = expf(slz[k]);

        float M00 = R00*s0, M01 = R01*s1, M02 = R02*s2;
        float M10 = R10*s0, M11 = R11*s1, M12 = R12*s2;
        float M20 = R20*s0, M21 = R21*s1, M22 = R22*s2;

        float cv00 = M00*M00 + M01*M01 + M02*M02;
        float cv01 = M00*M10 + M01*M11 + M02*M12;
        float cv02 = M00*M20 + M01*M21 + M02*M22;
        float cv11 = M10*M10 + M11*M11 + M12*M12;
        float cv12 = M10*M20 + M11*M21 + M12*M22;
        float cv22 = M20*M20 + M21*M21 + M22*M22;

        cov[9*k+0] = cv00; cov[9*k+1] = cv01; cov[9*k+2] = cv02;
        cov[9*k+3] = cv01; cov[9*k+4] = cv11; cov[9*k+5] = cv12;
        cov[9*k+6] = cv02; cov[9*k+7] = cv12; cov[9*k+8] = cv22;
    }

    // ---- coalesced 16B stores ----
    oxyz4[3*g+0] = pa;   // xyz is a pure pass-through copy
    oxyz4[3*g+1] = pb;
    oxyz4[3*g+2] = pc;

    #pragma unroll
    for (int j = 0; j < 9; ++j)
        ocov4[9*g+j] = make_float4(cov[4*j+0], cov[4*j+1], cov[4*j+2], cov[4*j+3]);

    orgb4[3*g+0] = make_float4(rgb[0], rgb[1], rgb[2],  rgb[3]);
    orgb4[3*g+1] = make_float4(rgb[4], rgb[5], rgb[6],  rgb[7]);
    orgb4[3*g+2] = make_float4(rgb[8], rgb[9], rgb[10], rgb[11]);

    oop4[g] = make_float4(opv[0], opv[1], opv[2], opv[3]);
}

// ---------------------------------------------------------------------------
// Scalar fallback (original kernel) for N % 4 != 0.
// ---------------------------------------------------------------------------
__global__ __launch_bounds__(256) void gauss_kernel(
    const float* __restrict__ view_dirs,
    const float* __restrict__ xyz,
    const float* __restrict__ scale_log,
    const float4* __restrict__ rot_quat,
    const float* __restrict__ opacity_logit,
    const float4* __restrict__ sh,
    float* __restrict__ out_xyz,
    float* __restrict__ out_cov,
    float* __restrict__ out_rgb,
    float* __restrict__ out_op,
    int N)
{
    int i = blockIdx.x * blockDim.x + threadIdx.x;
    if (i >= N) return;

    float vx = view_dirs[3*i+0], vy = view_dirs[3*i+1], vz = view_dirs[3*i+2];
    float px = xyz[3*i+0],       py = xyz[3*i+1],       pz = xyz[3*i+2];
    float sl0 = scale_log[3*i+0], sl1 = scale_log[3*i+1], sl2 = scale_log[3*i+2];
    float4 q  = rot_quat[i];
    float  ol = opacity_logit[i];
    float4 c0 = sh[3*i+0];
    float4 c1 = sh[3*i+1];
    float4 c2 = sh[3*i+2];

    float opacity = sigmoidf(ol);

    float r0 = C0*c0.x - C1*vy*c0.y + C1*vz*c0.z - C1*vx*c0.w;
    float r1 = C0*c1.x - C1*vy*c1.y + C1*vz*c1.z - C1*vx*c1.w;
    float r2 = C0*c2.x - C1*vy*c2.y + C1*vz*c2.z - C1*vx*c2.w;
    r0 = sigmoidf(r0); r1 = sigmoidf(r1); r2 = sigmoidf(r2);

    float nrm = sqrtf(q.x*q.x + q.y*q.y + q.z*q.z + q.w*q.w);
    float inv = 1.0f / fmaxf(nrm, 1e-12f);
    float r = q.x*inv, x = q.y*inv, y = q.z*inv, z = q.w*inv;

    float R00 = 1.0f - 2.0f*(y*y + z*z);
    float R01 = 2.0f*(x*y - r*z);
    float R02 = 2.0f*(x*z + r*y);
    float R10 = 2.0f*(x*y + r*z);
    float R11 = 1.0f - 2.0f*(x*x + z*z);
    float R12 = 2.0f*(y*z - r*x);
    float R20 = 2.0f*(x*z - r*y);
    float R21 = 2.0f*(y*z + r*x);
    float R22 = 1.0f - 2.0f*(x*x + y*y);

    float s0 = expf(sl0), s1 = expf(sl1), s2 = expf(sl2);

    float M00 = R00*s0, M01 = R01*s1, M02 = R02*s2;
    float M10 = R10*s0, M11 = R11*s1, M12 = R12*s2;
    float M20 = R20*s0, M21 = R21*s1, M22 = R22*s2;

    float cv00 = M00*M00 + M01*M01 + M02*M02;
    float cv01 = M00*M10 + M01*M11 + M02*M12;
    float cv02 = M00*M20 + M01*M21 + M02*M22;
    float cv11 = M10*M10 + M11*M11 + M12*M12;
    float cv12 = M10*M20 + M11*M21 + M12*M22;
    float cv22 = M20*M20 + M21*M21 + M22*M22;

    out_xyz[3*i+0] = px; out_xyz[3*i+1] = py; out_xyz[3*i+2] = pz;

    float* cp = out_cov + 9*i;
    cp[0] = cv00; cp[1] = cv01; cp[2] = cv02;
    cp[3] = cv01; cp[4] = cv11; cp[5] = cv12;
    cp[6] = cv02; cp[7] = cv12; cp[8] = cv22;

    out_rgb[3*i+0] = r0; out_rgb[3*i+1] = r1; out_rgb[3*i+2] = r2;
    out_op[i] = opacity;
}

extern "C" void kernel_launch(void* const* d_in, const int* in_sizes, int n_in,
                              void* d_out, int out_size, void* d_ws, size_t ws_size,
                              hipStream_t stream) {
    const float*  view_dirs     = (const float*)d_in[0];
    const float*  xyz           = (const float*)d_in[1];
    const float*  scale_log     = (const float*)d_in[2];
    const float4* rot_quat      = (const float4*)d_in[3];
    const float*  opacity_logit = (const float*)d_in[4];
    const float4* sh            = (const float4*)d_in[5];

    int N = in_sizes[4];  // opacity_logit has N elements

    float* out = (float*)d_out;
    float* out_xyz = out;                // N*3
    float* out_cov = out + (size_t)3*N;  // N*9
    float* out_rgb = out + (size_t)12*N; // N*3
    float* out_op  = out + (size_t)15*N; // N

    if ((N & 3) == 0) {
        int N4 = N >> 2;
        int block = 256;
        int grid = (N4 + block - 1) / block;
        gauss_kernel_v4<<<grid, block, 0, stream>>>(
            (const float4*)view_dirs, (const float4*)xyz, (const float4*)scale_log,
            rot_quat, (const float4*)opacity_logit, sh,
            (float4*)out_xyz, (float4*)out_cov, (float4*)out_rgb, (float4*)out_op,
            N4);
    } else {
        int block = 256;
        int grid = (N + block - 1) / block;
        gauss_kernel<<<grid, block, 0, stream>>>(view_dirs, xyz, scale_log, rot_quat,
                                                 opacity_logit, sh,
                                                 out_xyz, out_cov, out_rgb, out_op, N);
    }
}

// Round 4
// 286.511 us; speedup vs baseline: 1.1284x; 1.1284x over previous
//
#include <hip/hip_runtime.h>

#define C0 0.28209479177387814f
#define C1 0.4886025119029199f
#define BLK 256

__device__ __forceinline__ float sigmoidf(float x) {
    return 1.0f / (1.0f + expf(-x));
}

// ---------------------------------------------------------------------------
// LDS-transposed kernel: every global memory instruction is lane-contiguous
// (64 lanes x 4B/16B, full cache lines). The AoS (12B / 48B / 36B per
// element) <-> per-thread mismatch is resolved in LDS.
//
//   phase 1: flat coalesced loads  -> LDS   (vd, sl, sh[pad 12->13])
//   phase 2: per-thread compute (LDS -> regs; quat/op direct, coalesced)
//   phase 3: cov/rgb -> LDS (reused buffers) -> flat coalesced stores
//            xyz is a pure flat coalesced passthrough copy.
//
// Bank conflicts: all per-thread LDS strides (3, 9, 13) are odd -> 64 lanes
// map 2-per-bank -> free on CDNA4 (m136). Flat phases are stride-1.
// LDS = (13+3+3)*256*4 = 19 KB -> 8 blocks/CU possible.
// ---------------------------------------------------------------------------
__global__ __launch_bounds__(BLK) void gauss_kernel_lds(
    const float* __restrict__ view_dirs,
    const float* __restrict__ xyz,
    const float* __restrict__ scale_log,
    const float4* __restrict__ rot_quat,
    const float* __restrict__ opacity_logit,
    const float* __restrict__ sh,      // N*12 floats
    float* __restrict__ out_xyz,       // N*3
    float* __restrict__ out_cov,       // N*9
    float* __restrict__ out_rgb,       // N*3
    float* __restrict__ out_op,        // N
    int N)
{
    __shared__ float lds_sh[BLK * 13]; // in: sh (stride 13) ; reused: cov flat (BLK*9)
    __shared__ float lds_vd[BLK * 3];  // in: view_dirs      ; reused: rgb flat
    __shared__ float lds_sl[BLK * 3];  // in: scale_log

    const int t    = threadIdx.x;
    const int base = blockIdx.x * BLK;
    const int nblk = min(BLK, N - base);     // elements handled by this block
    const long b3  = (long)base * 3;
    const long b9  = (long)base * 9;
    const long b12 = (long)base * 12;

    // ---- phase 1: coalesced staging into LDS ----
    #pragma unroll
    for (int j = 0; j < 3; ++j) {
        int f = t + BLK * j;
        if (f < nblk * 3) {
            lds_vd[f] = view_dirs[b3 + f];
            lds_sl[f] = scale_log[b3 + f];
        }
    }
    #pragma unroll
    for (int j = 0; j < 12; ++j) {
        int f = t + BLK * j;
        if (f < nblk * 12) {
            // element e = f/12 goes to stride-13 slot: addr = f + e
            lds_sh[f + f / 12] = sh[b12 + f];
        }
    }
    __syncthreads();

    // ---- phase 2: LDS -> regs, then compute ----
    const bool active = (t < nblk);
    float vx = 0.f, vy = 0.f, vz = 0.f;
    float sl0 = 0.f, sl1 = 0.f, sl2 = 0.f;
    float c[12];
    float4 q = make_float4(1.f, 0.f, 0.f, 0.f);
    float ol = 0.f;
    #pragma unroll
    for (int m = 0; m < 12; ++m) c[m] = 0.f;

    if (active) {
        vx = lds_vd[3 * t + 0]; vy = lds_vd[3 * t + 1]; vz = lds_vd[3 * t + 2];
        sl0 = lds_sl[3 * t + 0]; sl1 = lds_sl[3 * t + 1]; sl2 = lds_sl[3 * t + 2];
        #pragma unroll
        for (int m = 0; m < 12; ++m) c[m] = lds_sh[13 * t + m];
        q  = rot_quat[base + t];              // 16B/elem: already coalesced
        ol = opacity_logit[base + t];         // 4B/elem: already coalesced
    }
    __syncthreads();  // all input-LDS reads done before buffers are reused

    if (active) {
        // rgb: degree-1 SH + sigmoid
        float r0 = C0 * c[0] - C1 * vy * c[1] + C1 * vz * c[2]  - C1 * vx * c[3];
        float r1 = C0 * c[4] - C1 * vy * c[5] + C1 * vz * c[6]  - C1 * vx * c[7];
        float r2 = C0 * c[8] - C1 * vy * c[9] + C1 * vz * c[10] - C1 * vx * c[11];
        r0 = sigmoidf(r0); r1 = sigmoidf(r1); r2 = sigmoidf(r2);

        // rotation from normalized quaternion
        float nrm = sqrtf(q.x * q.x + q.y * q.y + q.z * q.z + q.w * q.w);
        float inv = 1.0f / fmaxf(nrm, 1e-12f);
        float r = q.x * inv, x = q.y * inv, y = q.z * inv, z = q.w * inv;

        float R00 = 1.0f - 2.0f * (y * y + z * z);
        float R01 = 2.0f * (x * y - r * z);
        float R02 = 2.0f * (x * z + r * y);
        float R10 = 2.0f * (x * y + r * z);
        float R11 = 1.0f - 2.0f * (x * x + z * z);
        float R12 = 2.0f * (y * z - r * x);
        float R20 = 2.0f * (x * z - r * y);
        float R21 = 2.0f * (y * z + r * x);
        float R22 = 1.0f - 2.0f * (x * x + y * y);

        // M = R * diag(exp(scale_log)) ; cov = M M^T
        float s0 = expf(sl0), s1 = expf(sl1), s2 = expf(sl2);
        float M00 = R00 * s0, M01 = R01 * s1, M02 = R02 * s2;
        float M10 = R10 * s0, M11 = R11 * s1, M12 = R12 * s2;
        float M20 = R20 * s0, M21 = R21 * s1, M22 = R22 * s2;

        float cv00 = M00 * M00 + M01 * M01 + M02 * M02;
        float cv01 = M00 * M10 + M01 * M11 + M02 * M12;
        float cv02 = M00 * M20 + M01 * M21 + M02 * M22;
        float cv11 = M10 * M10 + M11 * M11 + M12 * M12;
        float cv12 = M10 * M20 + M11 * M21 + M12 * M22;
        float cv22 = M20 * M20 + M21 * M21 + M22 * M22;

        // outputs -> LDS (reused buffers), flat layout for coalesced store
        float* cov = lds_sh;   // BLK*9 floats, fits in BLK*13
        cov[9 * t + 0] = cv00; cov[9 * t + 1] = cv01; cov[9 * t + 2] = cv02;
        cov[9 * t + 3] = cv01; cov[9 * t + 4] = cv11; cov[9 * t + 5] = cv12;
        cov[9 * t + 6] = cv02; cov[9 * t + 7] = cv12; cov[9 * t + 8] = cv22;

        lds_vd[3 * t + 0] = r0; lds_vd[3 * t + 1] = r1; lds_vd[3 * t + 2] = r2;

        out_op[base + t] = sigmoidf(ol);      // direct coalesced store
    }
    __syncthreads();

    // ---- phase 3: flat coalesced stores + xyz passthrough ----
    #pragma unroll
    for (int j = 0; j < 3; ++j) {
        int f = t + BLK * j;
        if (f < nblk * 3) {
            out_xyz[b3 + f] = xyz[b3 + f];    // pure copy, both sides coalesced
            out_rgb[b3 + f] = lds_vd[f];
        }
    }
    #pragma unroll
    for (int j = 0; j < 9; ++j) {
        int f = t + BLK * j;
        if (f < nblk * 9) {
            out_cov[b9 + f] = lds_sh[f];
        }
    }
}

extern "C" void kernel_launch(void* const* d_in, const int* in_sizes, int n_in,
                              void* d_out, int out_size, void* d_ws, size_t ws_size,
                              hipStream_t stream) {
    const float*  view_dirs     = (const float*)d_in[0];
    const float*  xyz           = (const float*)d_in[1];
    const float*  scale_log     = (const float*)d_in[2];
    const float4* rot_quat      = (const float4*)d_in[3];
    const float*  opacity_logit = (const float*)d_in[4];
    const float*  sh            = (const float*)d_in[5];

    int N = in_sizes[4];  // opacity_logit has N elements

    float* out = (float*)d_out;
    float* out_xyz = out;                // N*3
    float* out_cov = out + (size_t)3*N;  // N*9
    float* out_rgb = out + (size_t)12*N; // N*3
    float* out_op  = out + (size_t)15*N; // N

    int grid = (N + BLK - 1) / BLK;
    gauss_kernel_lds<<<grid, BLK, 0, stream>>>(view_dirs, xyz, scale_log, rot_quat,
                                               opacity_logit, sh,
                                               out_xyz, out_cov, out_rgb, out_op, N);
}

// Round 6
// 285.401 us; speedup vs baseline: 1.1328x; 1.0039x over previous
//
#include <hip/hip_runtime.h>

#define C0 0.28209479177387814f
#define C1 0.4886025119029199f
#define BLK 256

// clang native vector type: __builtin_nontemporal_store requires a vector of
// scalars, not HIP's float4 class. Same 16B layout; reinterpret-cast is fine.
typedef float f4 __attribute__((ext_vector_type(4)));

__device__ __forceinline__ float sigmoidf(float x) {
    return 1.0f / (1.0f + expf(-x));
}

// ---------------------------------------------------------------------------
// LDS-transposed kernel, v2: all global traffic as float4 (1KB/wave per
// request, ~3.2x fewer VMEM instructions than the dword version) and
// nontemporal stores on every output (no-allocate -> the 128MB output stream
// does not evict the 208MB input set from the 256MB L3, so inputs stay
// L3-resident across bench dispatches).
//
//   phase 1: flat coalesced float4 loads -> LDS (vd, sl, sh at stride 13)
//   phase 2: per-thread compute (quat/op direct, already coalesced)
//   phase 3: cov/rgb via reused LDS -> flat coalesced float4 NT stores;
//            xyz = pure float4 copy.
//
// LDS strides: write sh at 13e+4c (incr 4,4,5 -> well spread); compute reads
// stride 13 (odd -> free 2-way); cov write stride 9 (odd); cov/rgb re-read as
// aligned float4. LDS = 19KB -> 8 blocks/CU.
// Fast path requires a full block AND N%4==0 (keeps out_cov/out_rgb/out_op
// bases 16B-aligned); tail block falls back to the scalar-dword path.
// ---------------------------------------------------------------------------
__global__ __launch_bounds__(BLK) void gauss_kernel_lds4(
    const float* __restrict__ view_dirs,
    const float* __restrict__ xyz,
    const float* __restrict__ scale_log,
    const float4* __restrict__ rot_quat,
    const float* __restrict__ opacity_logit,
    const float* __restrict__ sh,      // N*12 floats
    float* __restrict__ out_xyz,       // N*3
    float* __restrict__ out_cov,       // N*9
    float* __restrict__ out_rgb,       // N*3
    float* __restrict__ out_op,        // N
    int N)
{
    __shared__ float lds_sh[BLK * 13]; // in: sh (stride 13); reused: cov flat
    __shared__ float lds_vd[BLK * 3];  // in: view_dirs     ; reused: rgb flat
    __shared__ float lds_sl[BLK * 3];  // in: scale_log

    const int t    = threadIdx.x;
    const int base = blockIdx.x * BLK;
    const int nblk = min(BLK, N - base);
    const long b3  = (long)base * 3;
    const long b9  = (long)base * 9;
    const long b12 = (long)base * 12;
    const bool full = (nblk == BLK);

    // ---- phase 1: coalesced staging into LDS ----
    if (full) {
        const f4* vd4 = (const f4*)(view_dirs + b3);   // 192 float4
        const f4* sl4 = (const f4*)(scale_log + b3);   // 192 float4
        const f4* sh4 = (const f4*)(sh + b12);         // 768 float4
        if (t < 192) {
            f4 v = vd4[t];
            lds_vd[4*t+0] = v.x; lds_vd[4*t+1] = v.y;
            lds_vd[4*t+2] = v.z; lds_vd[4*t+3] = v.w;
            f4 s = sl4[t];
            lds_sl[4*t+0] = s.x; lds_sl[4*t+1] = s.y;
            lds_sl[4*t+2] = s.z; lds_sl[4*t+3] = s.w;
        }
        #pragma unroll
        for (int j = 0; j < 3; ++j) {
            int f4i = t + BLK * j;           // 0..767
            f4 v = sh4[f4i];
            int e = f4i / 3, c4 = f4i % 3;   // 3 float4 per element, no straddle
            int a = 13 * e + 4 * c4;
            lds_sh[a+0] = v.x; lds_sh[a+1] = v.y;
            lds_sh[a+2] = v.z; lds_sh[a+3] = v.w;
        }
    } else {
        #pragma unroll
        for (int j = 0; j < 3; ++j) {
            int f = t + BLK * j;
            if (f < nblk * 3) {
                lds_vd[f] = view_dirs[b3 + f];
                lds_sl[f] = scale_log[b3 + f];
            }
        }
        #pragma unroll
        for (int j = 0; j < 12; ++j) {
            int f = t + BLK * j;
            if (f < nblk * 12) lds_sh[f + f / 12] = sh[b12 + f];
        }
    }
    __syncthreads();

    // ---- phase 2: LDS -> regs, then compute ----
    const bool active = (t < nblk);
    float vx = 0.f, vy = 0.f, vz = 0.f;
    float sl0 = 0.f, sl1 = 0.f, sl2 = 0.f;
    float c[12];
    float4 q = make_float4(1.f, 0.f, 0.f, 0.f);
    float ol = 0.f;
    #pragma unroll
    for (int m = 0; m < 12; ++m) c[m] = 0.f;

    if (active) {
        vx = lds_vd[3*t+0]; vy = lds_vd[3*t+1]; vz = lds_vd[3*t+2];
        sl0 = lds_sl[3*t+0]; sl1 = lds_sl[3*t+1]; sl2 = lds_sl[3*t+2];
        #pragma unroll
        for (int m = 0; m < 12; ++m) c[m] = lds_sh[13*t + m];
        q  = rot_quat[base + t];          // 16B/elem: already coalesced
        ol = opacity_logit[base + t];     // 4B/elem: already coalesced
    }
    __syncthreads();  // input-LDS reads done; buffers may be reused

    if (active) {
        float r0 = C0*c[0] - C1*vy*c[1] + C1*vz*c[2]  - C1*vx*c[3];
        float r1 = C0*c[4] - C1*vy*c[5] + C1*vz*c[6]  - C1*vx*c[7];
        float r2 = C0*c[8] - C1*vy*c[9] + C1*vz*c[10] - C1*vx*c[11];
        r0 = sigmoidf(r0); r1 = sigmoidf(r1); r2 = sigmoidf(r2);

        float nrm = sqrtf(q.x*q.x + q.y*q.y + q.z*q.z + q.w*q.w);
        float inv = 1.0f / fmaxf(nrm, 1e-12f);
        float r = q.x*inv, x = q.y*inv, y = q.z*inv, z = q.w*inv;

        float R00 = 1.0f - 2.0f*(y*y + z*z);
        float R01 = 2.0f*(x*y - r*z);
        float R02 = 2.0f*(x*z + r*y);
        float R10 = 2.0f*(x*y + r*z);
        float R11 = 1.0f - 2.0f*(x*x + z*z);
        float R12 = 2.0f*(y*z - r*x);
        float R20 = 2.0f*(x*z - r*y);
        float R21 = 2.0f*(y*z + r*x);
        float R22 = 1.0f - 2.0f*(x*x + y*y);

        float s0 = expf(sl0), s1 = expf(sl1), s2 = expf(sl2);
        float M00 = R00*s0, M01 = R01*s1, M02 = R02*s2;
        float M10 = R10*s0, M11 = R11*s1, M12 = R12*s2;
        float M20 = R20*s0, M21 = R21*s1, M22 = R22*s2;

        float cv00 = M00*M00 + M01*M01 + M02*M02;
        float cv01 = M00*M10 + M01*M11 + M02*M12;
        float cv02 = M00*M20 + M01*M21 + M02*M22;
        float cv11 = M10*M10 + M11*M11 + M12*M12;
        float cv12 = M10*M20 + M11*M21 + M12*M22;
        float cv22 = M20*M20 + M21*M21 + M22*M22;

        float* cov = lds_sh;   // BLK*9 floats flat
        cov[9*t+0] = cv00; cov[9*t+1] = cv01; cov[9*t+2] = cv02;
        cov[9*t+3] = cv01; cov[9*t+4] = cv11; cov[9*t+5] = cv12;
        cov[9*t+6] = cv02; cov[9*t+7] = cv12; cov[9*t+8] = cv22;

        lds_vd[3*t+0] = r0; lds_vd[3*t+1] = r1; lds_vd[3*t+2] = r2;

        __builtin_nontemporal_store(sigmoidf(ol), out_op + base + t);
    }
    __syncthreads();

    // ---- phase 3: flat coalesced stores + xyz passthrough ----
    if (full) {
        const f4* xi4 = (const f4*)(xyz     + b3);
        f4* ox4 = (f4*)(out_xyz + b3);
        f4* or4 = (f4*)(out_rgb + b3);
        f4* oc4 = (f4*)(out_cov + b9);
        if (t < 192) {
            f4 p = xi4[t];
            __builtin_nontemporal_store(p, ox4 + t);
            f4 rg = *(const f4*)(lds_vd + 4*t);           // 16B-aligned
            __builtin_nontemporal_store(rg, or4 + t);
        }
        #pragma unroll
        for (int j = 0; j < 3; ++j) {
            int f4i = t + BLK * j;           // 0..767; cov has 576 float4
            if (f4i < 576) {
                f4 cv = *(const f4*)(lds_sh + 4*f4i);     // 16B-aligned
                __builtin_nontemporal_store(cv, oc4 + f4i);
            }
        }
    } else {
        #pragma unroll
        for (int j = 0; j < 3; ++j) {
            int f = t + BLK * j;
            if (f < nblk * 3) {
                __builtin_nontemporal_store(xyz[b3 + f], out_xyz + b3 + f);
                __builtin_nontemporal_store(lds_vd[f],  out_rgb + b3 + f);
            }
        }
        #pragma unroll
        for (int j = 0; j < 9; ++j) {
            int f = t + BLK * j;
            if (f < nblk * 9)
                __builtin_nontemporal_store(lds_sh[f], out_cov + b9 + f);
        }
    }
}

// ---------------------------------------------------------------------------
// Pure scalar fallback (only used when N%4 != 0, where the packed output
// sub-buffer bases are not 16B-aligned).
// ---------------------------------------------------------------------------
__global__ __launch_bounds__(BLK) void gauss_kernel_scalar(
    const float* __restrict__ view_dirs,
    const float* __restrict__ xyz,
    const float* __restrict__ scale_log,
    const float4* __restrict__ rot_quat,
    const float* __restrict__ opacity_logit,
    const float4* __restrict__ sh,
    float* __restrict__ out_xyz,
    float* __restrict__ out_cov,
    float* __restrict__ out_rgb,
    float* __restrict__ out_op,
    int N)
{
    int i = blockIdx.x * blockDim.x + threadIdx.x;
    if (i >= N) return;

    float vx = view_dirs[3*i+0], vy = view_dirs[3*i+1], vz = view_dirs[3*i+2];
    float px = xyz[3*i+0], py = xyz[3*i+1], pz = xyz[3*i+2];
    float sl0 = scale_log[3*i+0], sl1 = scale_log[3*i+1], sl2 = scale_log[3*i+2];
    float4 q = rot_quat[i];
    float ol = opacity_logit[i];
    float4 c0 = sh[3*i+0], c1 = sh[3*i+1], c2 = sh[3*i+2];

    float opacity = sigmoidf(ol);
    float r0 = sigmoidf(C0*c0.x - C1*vy*c0.y + C1*vz*c0.z - C1*vx*c0.w);
    float r1 = sigmoidf(C0*c1.x - C1*vy*c1.y + C1*vz*c1.z - C1*vx*c1.w);
    float r2 = sigmoidf(C0*c2.x - C1*vy*c2.y + C1*vz*c2.z - C1*vx*c2.w);

    float nrm = sqrtf(q.x*q.x + q.y*q.y + q.z*q.z + q.w*q.w);
    float inv = 1.0f / fmaxf(nrm, 1e-12f);
    float r = q.x*inv, x = q.y*inv, y = q.z*inv, z = q.w*inv;

    float R00 = 1.0f - 2.0f*(y*y + z*z), R01 = 2.0f*(x*y - r*z), R02 = 2.0f*(x*z + r*y);
    float R10 = 2.0f*(x*y + r*z), R11 = 1.0f - 2.0f*(x*x + z*z), R12 = 2.0f*(y*z - r*x);
    float R20 = 2.0f*(x*z - r*y), R21 = 2.0f*(y*z + r*x), R22 = 1.0f - 2.0f*(x*x + y*y);

    float s0 = expf(sl0), s1 = expf(sl1), s2 = expf(sl2);
    float M00 = R00*s0, M01 = R01*s1, M02 = R02*s2;
    float M10 = R10*s0, M11 = R11*s1, M12 = R12*s2;
    float M20 = R20*s0, M21 = R21*s1, M22 = R22*s2;

    float cv00 = M00*M00 + M01*M01 + M02*M02;
    float cv01 = M00*M10 + M01*M11 + M02*M12;
    float cv02 = M00*M20 + M01*M21 + M02*M22;
    float cv11 = M10*M10 + M11*M11 + M12*M12;
    float cv12 = M10*M20 + M11*M21 + M12*M22;
    float cv22 = M20*M20 + M21*M21 + M22*M22;

    out_xyz[3*i+0] = px; out_xyz[3*i+1] = py; out_xyz[3*i+2] = pz;
    float* cp = out_cov + 9*i;
    cp[0] = cv00; cp[1] = cv01; cp[2] = cv02;
    cp[3] = cv01; cp[4] = cv11; cp[5] = cv12;
    cp[6] = cv02; cp[7] = cv12; cp[8] = cv22;
    out_rgb[3*i+0] = r0; out_rgb[3*i+1] = r1; out_rgb[3*i+2] = r2;
    out_op[i] = opacity;
}

extern "C" void kernel_launch(void* const* d_in, const int* in_sizes, int n_in,
                              void* d_out, int out_size, void* d_ws, size_t ws_size,
                              hipStream_t stream) {
    const float*  view_dirs     = (const float*)d_in[0];
    const float*  xyz           = (const float*)d_in[1];
    const float*  scale_log     = (const float*)d_in[2];
    const float4* rot_quat      = (const float4*)d_in[3];
    const float*  opacity_logit = (const float*)d_in[4];
    const float*  sh            = (const float*)d_in[5];

    int N = in_sizes[4];  // opacity_logit has N elements

    float* out = (float*)d_out;
    float* out_xyz = out;                // N*3
    float* out_cov = out + (size_t)3*N;  // N*9
    float* out_rgb = out + (size_t)12*N; // N*3
    float* out_op  = out + (size_t)15*N; // N

    int grid = (N + BLK - 1) / BLK;
    if ((N & 3) == 0) {
        gauss_kernel_lds4<<<grid, BLK, 0, stream>>>(view_dirs, xyz, scale_log,
                                                    rot_quat, opacity_logit, sh,
                                                    out_xyz, out_cov, out_rgb,
                                                    out_op, N);
    } else {
        gauss_kernel_scalar<<<grid, BLK, 0, stream>>>(view_dirs, xyz, scale_log,
                                                      rot_quat, opacity_logit,
                                                      (const float4*)sh,
                                                      out_xyz, out_cov, out_rgb,
                                                      out_op, N);
    }
}